// Round 1
// baseline (644.540 us; speedup 1.0000x reference)
//
#include <hip/hip_runtime.h>
#include <stdint.h>
#include <math.h>

// MoE FFN: x[4096,1024], top-2 of 8 experts, W1[E,1024,4096], W2[E,4096,1024]
// Sparse bf16-MFMA implementation. Workspace need ~218 MB.

#define D_MODEL 1024
#define D_FF    4096
#define NEXP    8
#define MAXN    4096
#define MAXROWS (2*MAXN + NEXP*128)   // 9216 padded rows max
#define BM 128
#define BN 128
#define BK 64
#define MAXRT (MAXROWS/BM)            // 72 row tiles

typedef __attribute__((ext_vector_type(8))) short bf16x8;  // 8 bf16 = 4 VGPRs
typedef __attribute__((ext_vector_type(4))) float f32x4;

__device__ __forceinline__ unsigned short f2bf(float f) {
  union { float f; uint32_t u; } v; v.f = f;
  uint32_t u = v.u;
  uint32_t r = (u + 0x7FFFu + ((u >> 16) & 1u)) >> 16;  // RNE
  return (unsigned short)r;
}

#define GLOAD_LDS16(src, dst) \
  __builtin_amdgcn_global_load_lds((const __attribute__((address_space(1))) void*)(src), \
                                   (__attribute__((address_space(3))) void*)(dst), 16, 0, 0)

// ---------------- gate: fp32 logits -> softmax -> top2 -> per-expert lists ----------------
__global__ __launch_bounds__(256) void gate_kernel(
    const float* __restrict__ x, const float* __restrict__ gw, int N,
    int* __restrict__ counts, int* __restrict__ toklist, float* __restrict__ wlist) {
  int lane = threadIdx.x & 63;
  int wid  = threadIdx.x >> 6;
  int n = blockIdx.x * 4 + wid;
  if (n >= N) return;
  const float* xr = x + (size_t)n * D_MODEL;
  float p[NEXP];
#pragma unroll
  for (int e = 0; e < NEXP; ++e) p[e] = 0.f;
  for (int i = lane; i < D_MODEL; i += 64) {
    float xv = xr[i];
#pragma unroll
    for (int e = 0; e < NEXP; ++e) p[e] += xv * gw[e * D_MODEL + i];
  }
#pragma unroll
  for (int e = 0; e < NEXP; ++e) {
#pragma unroll
    for (int off = 32; off > 0; off >>= 1) p[e] += __shfl_xor(p[e], off);
  }
  if (lane == 0) {
    float m = p[0];
#pragma unroll
    for (int e = 1; e < NEXP; ++e) m = fmaxf(m, p[e]);
    float sc[NEXP]; float s = 0.f;
#pragma unroll
    for (int e = 0; e < NEXP; ++e) { sc[e] = expf(p[e] - m); s += sc[e]; }
    float inv = 1.f / s;
    int i0 = 0; float b0 = sc[0];
#pragma unroll
    for (int e = 1; e < NEXP; ++e) if (sc[e] > b0) { b0 = sc[e]; i0 = e; }
    int i1 = -1; float b1 = -1.f;
#pragma unroll
    for (int e = 0; e < NEXP; ++e) if (e != i0 && sc[e] > b1) { b1 = sc[e]; i1 = e; }
    int p0 = atomicAdd(&counts[i0], 1);
    toklist[i0 * MAXN + p0] = n; wlist[i0 * MAXN + p0] = b0 * inv;
    int p1 = atomicAdd(&counts[i1], 1);
    toklist[i1 * MAXN + p1] = n; wlist[i1 * MAXN + p1] = b1 * inv;
  }
}

// ---------------- offsets (padded to BM) ----------------
__global__ void offsets_kernel(const int* __restrict__ counts, int* __restrict__ off_pad) {
  if (threadIdx.x == 0 && blockIdx.x == 0) {
    int o = 0; off_pad[0] = 0;
    for (int e = 0; e < NEXP; ++e) { o += (counts[e] + BM - 1) & ~(BM - 1); off_pad[e + 1] = o; }
  }
}

__global__ __launch_bounds__(128) void fill_rows(
    const int* __restrict__ counts, const int* __restrict__ off_pad,
    const int* __restrict__ toklist, const float* __restrict__ wlist,
    int* __restrict__ row_token, float* __restrict__ row_weight) {
  int e = blockIdx.x; int pos = blockIdx.y * 128 + threadIdx.x;
  int base = off_pad[e]; int span = off_pad[e + 1] - base;
  if (pos >= span) return;
  int cnt = counts[e];
  if (pos < cnt) { row_token[base + pos] = toklist[e * MAXN + pos]; row_weight[base + pos] = wlist[e * MAXN + pos]; }
  else           { row_token[base + pos] = 0;                        row_weight[base + pos] = 0.f; }
}

// ---------------- fp32 -> bf16 convert (linear) ----------------
__global__ __launch_bounds__(256) void cvt_x(const float* __restrict__ in,
                                             unsigned short* __restrict__ out, int n4) {
  int i = blockIdx.x * 256 + threadIdx.x;
  if (i >= n4) return;
  float4 v = ((const float4*)in)[i];
  ushort4 o; o.x = f2bf(v.x); o.y = f2bf(v.y); o.z = f2bf(v.z); o.w = f2bf(v.w);
  ((ushort4*)out)[i] = o;
}

// ---------------- fp32 [R][C] -> bf16 [C][R] transpose-convert, per expert z ----------------
__global__ __launch_bounds__(256) void transpose_cvt(const float* __restrict__ in,
                                                     unsigned short* __restrict__ out,
                                                     int R, int C) {
  __shared__ float tile[64][65];
  size_t es = (size_t)R * C;
  in  += (size_t)blockIdx.z * es;
  out += (size_t)blockIdx.z * es;
  int c0 = blockIdx.x * 64, r0 = blockIdx.y * 64;
  int t = threadIdx.x;
  int rl = t >> 4, cq = (t & 15) * 4;
#pragma unroll
  for (int p = 0; p < 4; ++p) {
    int row = p * 16 + rl;
    float4 v = *(const float4*)(in + (size_t)(r0 + row) * C + c0 + cq);
    tile[row][cq] = v.x; tile[row][cq + 1] = v.y; tile[row][cq + 2] = v.z; tile[row][cq + 3] = v.w;
  }
  __syncthreads();
#pragma unroll
  for (int p = 0; p < 4; ++p) {
    int cl = p * 16 + rl;
    ushort4 o;
    o.x = f2bf(tile[cq][cl]); o.y = f2bf(tile[cq + 1][cl]);
    o.z = f2bf(tile[cq + 2][cl]); o.w = f2bf(tile[cq + 3][cl]);
    *(ushort4*)(out + (size_t)(c0 + cl) * R + r0 + cq) = o;
  }
}

// ---------------- MFMA GEMM: C[rows, Ncols] = A[rows,K] * B_e^T (B stored [E][Ncols][K]) -----
// GATHER: A rows gathered via row_token (GEMM1, A=xb). else A rows direct (GEMM2, A=h).
// EPI 1: h[row*D_FF+col] = bf16(gelu(acc)).  EPI 2: atomicAdd(out[tok*D+col], acc*w).
template<bool GATHER, int EPI>
__global__ __launch_bounds__(256, 2) void gemm_moe(
    const unsigned short* __restrict__ A, const unsigned short* __restrict__ B,
    int K, int Ncols, const int* __restrict__ off_pad,
    const int* __restrict__ row_token, const float* __restrict__ row_weight,
    unsigned short* __restrict__ hout, float* __restrict__ out) {
  __shared__ alignas(16) unsigned short Atile[BM * BK];
  __shared__ alignas(16) unsigned short Btile[BN * BK];
  int row0 = blockIdx.y * BM;
  int total = off_pad[NEXP];
  if (row0 >= total) return;
  int e = 0;
#pragma unroll
  for (int q = 1; q < NEXP; ++q) if (row0 >= off_pad[q]) e = q;
  int n0 = blockIdx.x * BN;
  int tid = threadIdx.x, lane = tid & 63, wid = tid >> 6;
  int wm = wid >> 1, wn = wid & 1;

  // staging addresses: chunk g = j*64+lane; row = g/8, chunk c = g%8; swizzled source.
  const char* aSrc[4]; const char* bSrc[4]; char* aDst[4]; char* bDst[4];
#pragma unroll
  for (int i = 0; i < 4; ++i) {
    int j = wid * 4 + i;
    int grow = j * 8 + (lane >> 3);
    int c = lane & 7;
    int swz = ((c ^ (grow & 7)) << 4);
    size_t arow = GATHER ? (size_t)row_token[row0 + grow] : (size_t)(row0 + grow);
    aSrc[i] = (const char*)A + arow * (size_t)K * 2 + swz;
    size_t brow = (size_t)e * (size_t)Ncols * K + (size_t)(n0 + grow) * K;
    bSrc[i] = (const char*)B + brow * 2 + swz;
    aDst[i] = (char*)Atile + j * 1024;
    bDst[i] = (char*)Btile + j * 1024;
  }

  f32x4 acc[4][4];
  f32x4 zero = {0.f, 0.f, 0.f, 0.f};
#pragma unroll
  for (int m = 0; m < 4; ++m)
#pragma unroll
    for (int n = 0; n < 4; ++n) acc[m][n] = zero;

  int nkt = K / BK;
  for (int kt = 0; kt < nkt; ++kt) {
    size_t koff = (size_t)kt * (BK * 2);  // 128B per row per k-tile
#pragma unroll
    for (int i = 0; i < 4; ++i) {
      GLOAD_LDS16(aSrc[i] + koff, aDst[i]);
      GLOAD_LDS16(bSrc[i] + koff, bDst[i]);
    }
    __syncthreads();  // drains vmcnt before barrier (compiler-inserted)
#pragma unroll
    for (int kk = 0; kk < 2; ++kk) {
      bf16x8 af[4], bf[4];
#pragma unroll
      for (int m = 0; m < 4; ++m) {
        int row = wm * 64 + m * 16 + (lane & 15);
        int ch = kk * 4 + (lane >> 4);
        af[m] = *(const bf16x8*)((const char*)Atile + row * 128 + ((ch ^ (row & 7)) << 4));
      }
#pragma unroll
      for (int n = 0; n < 4; ++n) {
        int row = wn * 64 + n * 16 + (lane & 15);
        int ch = kk * 4 + (lane >> 4);
        bf[n] = *(const bf16x8*)((const char*)Btile + row * 128 + ((ch ^ (row & 7)) << 4));
      }
#pragma unroll
      for (int m = 0; m < 4; ++m)
#pragma unroll
        for (int n = 0; n < 4; ++n)
          acc[m][n] = __builtin_amdgcn_mfma_f32_16x16x32_bf16(af[m], bf[n], acc[m][n], 0, 0, 0);
    }
    __syncthreads();
  }

  if (EPI == 1) {
#pragma unroll
    for (int m = 0; m < 4; ++m) {
#pragma unroll
      for (int j = 0; j < 4; ++j) {
        int grow = row0 + wm * 64 + m * 16 + (lane >> 4) * 4 + j;
        size_t rb = (size_t)grow * D_FF;
#pragma unroll
        for (int n = 0; n < 4; ++n) {
          int col = n0 + wn * 64 + n * 16 + (lane & 15);
          float v = acc[m][n][j];
          v = 0.5f * v * (1.f + erff(v * 0.70710678118654752f));
          hout[rb + col] = f2bf(v);
        }
      }
    }
  } else {
#pragma unroll
    for (int m = 0; m < 4; ++m) {
#pragma unroll
      for (int j = 0; j < 4; ++j) {
        int r = row0 + wm * 64 + m * 16 + (lane >> 4) * 4 + j;
        float w = row_weight[r];
        int tok = row_token[r];
        if (w != 0.f) {
          float* orow = out + (size_t)tok * D_MODEL;
#pragma unroll
          for (int n = 0; n < 4; ++n) {
            int col = n0 + wn * 64 + n * 16 + (lane & 15);
            atomicAdd(orow + col, acc[m][n][j] * w);
          }
        }
      }
    }
  }
}

extern "C" void kernel_launch(void* const* d_in, const int* in_sizes, int n_in,
                              void* d_out, int out_size, void* d_ws, size_t ws_size,
                              hipStream_t stream) {
  const float* x  = (const float*)d_in[0];
  const float* gw = (const float*)d_in[1];
  const float* W1 = (const float*)d_in[2];
  const float* W2 = (const float*)d_in[3];
  float* out = (float*)d_out;
  int N = in_sizes[0] / D_MODEL;  // 4096

  char* ws = (char*)d_ws;
  size_t o = 0;
  auto alloc = [&](size_t b) { size_t r = o; o += (b + 255) & ~255ULL; return r; };
  int*            counts    = (int*)(ws + alloc(NEXP * 4));
  int*            off_pad   = (int*)(ws + alloc((NEXP + 1) * 4));
  int*            toklist   = (int*)(ws + alloc((size_t)NEXP * MAXN * 4));
  float*          wlist     = (float*)(ws + alloc((size_t)NEXP * MAXN * 4));
  int*            row_token = (int*)(ws + alloc(MAXROWS * 4));
  float*          row_weight= (float*)(ws + alloc(MAXROWS * 4));
  unsigned short* xb        = (unsigned short*)(ws + alloc((size_t)N * D_MODEL * 2));
  unsigned short* w1t       = (unsigned short*)(ws + alloc((size_t)NEXP * D_MODEL * D_FF * 2));
  unsigned short* w2t       = (unsigned short*)(ws + alloc((size_t)NEXP * D_MODEL * D_FF * 2));
  unsigned short* h         = (unsigned short*)(ws + alloc((size_t)MAXROWS * D_FF * 2));
  (void)ws_size; (void)n_in;

  hipMemsetAsync(counts, 0, NEXP * sizeof(int), stream);
  hipMemsetAsync(d_out, 0, (size_t)out_size * sizeof(float), stream);

  gate_kernel<<<N / 4, 256, 0, stream>>>(x, gw, N, counts, toklist, wlist);
  offsets_kernel<<<1, 1, 0, stream>>>(counts, off_pad);
  fill_rows<<<dim3(NEXP, MAXN / 128), 128, 0, stream>>>(counts, off_pad, toklist, wlist, row_token, row_weight);
  cvt_x<<<(N * D_MODEL / 4 + 255) / 256, 256, 0, stream>>>(x, xb, N * D_MODEL / 4);
  transpose_cvt<<<dim3(D_FF / 64, D_MODEL / 64, NEXP), 256, 0, stream>>>(W1, w1t, D_MODEL, D_FF);
  transpose_cvt<<<dim3(D_MODEL / 64, D_FF / 64, NEXP), 256, 0, stream>>>(W2, w2t, D_FF, D_MODEL);
  gemm_moe<true, 1><<<dim3(D_FF / BN, MAXRT), 256, 0, stream>>>(
      xb, w1t, D_MODEL, D_FF, off_pad, row_token, row_weight, h, nullptr);
  gemm_moe<false, 2><<<dim3(D_MODEL / BN, MAXRT), 256, 0, stream>>>(
      h, w2t, D_FF, D_MODEL, off_pad, row_token, row_weight, nullptr, out);
}